// Round 2
// baseline (171.289 us; speedup 1.0000x reference)
//
#include <hip/hip_runtime.h>
#include <stdint.h>

// ---------- types ----------
typedef __attribute__((ext_vector_type(8))) __bf16 bf16x8;   // MFMA A/B frag (4 VGPRs)
typedef __attribute__((ext_vector_type(4))) float  floatx4;  // MFMA C/D frag
typedef __attribute__((ext_vector_type(4))) unsigned int uint4v;
typedef __attribute__((ext_vector_type(4))) float  float4v;

__device__ __forceinline__ float bf2f(unsigned short h) {
  union { unsigned int u; float f; } x; x.u = ((unsigned int)h) << 16; return x.f;
}
__device__ __forceinline__ unsigned short f2bf(float f) {
  union { float f; unsigned int u; } x; x.f = f;
  unsigned int r = x.u + 0x7fffu + ((x.u >> 16) & 1u);  // RNE
  return (unsigned short)(r >> 16);
}

// ---------------- kernel 1: start/end logits (pure fp32) ----------------
// grid 32 x 256 threads = 128 waves; each wave does 4 rows (512 rows total).
__global__ __launch_bounds__(256) void logits_kernel(
    const float* __restrict__ hidden,   // [512,768] fp32
    const float* __restrict__ w_start,  // [768]
    const float* __restrict__ b_start,  // [1]
    const float* __restrict__ w_end,    // [768]
    const float* __restrict__ b_end,    // [1]
    float* __restrict__ out) {          // out[0..511] start, [512..1023] end
  const int tid  = threadIdx.x;
  const int lane = tid & 63;
  const int wv   = tid >> 6;
  const int wg   = blockIdx.x * 4 + wv;  // 0..127

  float wsv[12], wev[12];
#pragma unroll
  for (int t = 0; t < 12; ++t) {
    wsv[t] = w_start[lane + 64 * t];
    wev[t] = w_end[lane + 64 * t];
  }
  const float bs = b_start[0];
  const float be = b_end[0];

#pragma unroll
  for (int r = 0; r < 4; ++r) {
    int row = wg * 4 + r;
    const float* h = hidden + (size_t)row * 768;
    float ps = 0.f, pe = 0.f;
#pragma unroll
    for (int t = 0; t < 12; ++t) {
      float hv = h[lane + 64 * t];
      ps += hv * wsv[t];
      pe += hv * wev[t];
    }
#pragma unroll
    for (int off = 32; off >= 1; off >>= 1) {
      ps += __shfl_xor(ps, off, 64);
      pe += __shfl_xor(pe, off, 64);
    }
    if (lane == 0) {
      out[row]       = ps + bs;
      out[512 + row] = pe + be;
    }
  }
}

// ---------------- kernel 2: projections via bf16 MFMA (fp32 in, bf16 ws out) ----------------
// R[m,n] = sum_k hidden[m,k]*w1[k,n] + b1[n]        (z==0)
// C[m,n] = sum_k hidden[m,k]*w1[768+k,n]            (z==1)
// grid (24 n-tiles, 8 m-tiles, 2 halves), 256 threads = 4 waves, 64x64 block tile,
// each wave a 32x32 quadrant (2x2 of 16x16x32 MFMA). K-loop: 24 x BK=32.
// LDS is fragment-direct: index (kgroup*64+row)*8+j -> frag reads are contiguous b128.
__global__ __launch_bounds__(256, 4) void proj_kernel(
    const float* __restrict__ hidden,   // [512,768] fp32
    const float* __restrict__ w1,       // [1536,1536] fp32
    const float* __restrict__ b1,       // [1536] fp32
    unsigned short* __restrict__ wsR,   // [512,1536] bf16
    unsigned short* __restrict__ wsC) { // [512,1536] bf16
  __shared__ short As[4 * 64 * 8];  // A[row][ko+q*8+j] at (q*64+row)*8+j
  __shared__ short Bs[4 * 64 * 8];  // B[ko+q*8+j][n]   at (q*64+n  )*8+j

  const int tid  = threadIdx.x;
  const int lane = tid & 63;
  const int wave = tid >> 6;
  const int wr = wave >> 1, wc = wave & 1;
  const int m0 = blockIdx.y * 64;
  const int n0 = blockIdx.x * 64;
  const int zh = blockIdx.z;
  const int kbase = zh * 768;

  floatx4 acc[2][2] = {};

  const int a_row = tid >> 2;   // 0..63
  const int a_q   = tid & 3;    // 0..3 (K-group of 8)
  const int b_n   = tid & 63;   // 0..63
  const int b_kg  = tid >> 6;   // 0..3

  const int q   = lane >> 4;
  const int l15 = lane & 15;

  for (int ko = 0; ko < 768; ko += 32) {
    // --- stage A: 32B coalesced fp32 load -> bf16 pack -> one b128 LDS write
    const float* hp = hidden + (size_t)(m0 + a_row) * 768 + ko + a_q * 8;
    float4v h0 = *(const float4v*)(hp);
    float4v h1 = *(const float4v*)(hp + 4);
    uint4v av;
    av[0] = (unsigned int)f2bf(h0[0]) | ((unsigned int)f2bf(h0[1]) << 16);
    av[1] = (unsigned int)f2bf(h0[2]) | ((unsigned int)f2bf(h0[3]) << 16);
    av[2] = (unsigned int)f2bf(h1[0]) | ((unsigned int)f2bf(h1[1]) << 16);
    av[3] = (unsigned int)f2bf(h1[2]) | ((unsigned int)f2bf(h1[3]) << 16);
    *(uint4v*)(&As[(a_q * 64 + a_row) * 8]) = av;

    // --- stage B (transpose in-register): 8 strided-coalesced 4B loads, cvt+pack, 1 b128 write
    const float* bp = w1 + (size_t)(kbase + ko + b_kg * 8) * 1536 + n0 + b_n;
    uint4v pv;
#pragma unroll
    for (int a = 0; a < 4; ++a) {
      unsigned int lo = f2bf(bp[(size_t)(2 * a) * 1536]);
      unsigned int hi = f2bf(bp[(size_t)(2 * a + 1) * 1536]);
      pv[a] = lo | (hi << 16);
    }
    *(uint4v*)(&Bs[(b_kg * 64 + b_n) * 8]) = pv;

    __syncthreads();

    bf16x8 af0 = *(const bf16x8*)(&As[(q * 64 + 32 * wr + l15) * 8]);
    bf16x8 af1 = *(const bf16x8*)(&As[(q * 64 + 32 * wr + 16 + l15) * 8]);
    bf16x8 bg0 = *(const bf16x8*)(&Bs[(q * 64 + 32 * wc + l15) * 8]);
    bf16x8 bg1 = *(const bf16x8*)(&Bs[(q * 64 + 32 * wc + 16 + l15) * 8]);

    acc[0][0] = __builtin_amdgcn_mfma_f32_16x16x32_bf16(af0, bg0, acc[0][0], 0, 0, 0);
    acc[0][1] = __builtin_amdgcn_mfma_f32_16x16x32_bf16(af0, bg1, acc[0][1], 0, 0, 0);
    acc[1][0] = __builtin_amdgcn_mfma_f32_16x16x32_bf16(af1, bg0, acc[1][0], 0, 0, 0);
    acc[1][1] = __builtin_amdgcn_mfma_f32_16x16x32_bf16(af1, bg1, acc[1][1], 0, 0, 0);

    __syncthreads();
  }

  // epilogue: C/D layout col = lane&15, row = (lane>>4)*4 + reg  [m89-verified]
  unsigned short* outp = (zh == 0) ? wsR : wsC;
#pragma unroll
  for (int mi = 0; mi < 2; ++mi) {
#pragma unroll
    for (int ni = 0; ni < 2; ++ni) {
      int colg = n0 + 32 * wc + 16 * ni + l15;
      float bias = (zh == 0) ? b1[colg] : 0.0f;
#pragma unroll
      for (int r = 0; r < 4; ++r) {
        int rowg = m0 + 32 * wr + 16 * mi + q * 4 + r;
        outp[(size_t)rowg * 1536 + colg] = f2bf(acc[mi][ni][r] + bias);
      }
    }
  }
}

// ---------------- kernel 3: pairwise gelu-match ----------------
// match[b,i,j] = sum_k gelu(R[b,i,k] + C[b,j,k]) * w2[k] + b2
// grid (16 jt, 16 it, 2 b) = 512 blocks, 256 thr, 1 output/thread.
// LDS: fp32 R/C tiles (stride 516: conflict-free / 2-way), K chunked 3x512. 68KB -> 2 blk/CU.
__global__ __launch_bounds__(256, 2) void match_kernel(
    const unsigned short* __restrict__ wsR,
    const unsigned short* __restrict__ wsC,
    const float* __restrict__ w2,   // [1536] fp32
    const float* __restrict__ b2,   // [1]
    float* __restrict__ out) {      // d_out + 1024, [2,256,256] fp32
  __shared__ float Rs[16 * 516];
  __shared__ float Cs[16 * 516];
  __shared__ float Ws[512];

  const int tid = threadIdx.x;
  const int jt = blockIdx.x, it = blockIdx.y, bz = blockIdx.z;
  const int i = tid >> 4, j = tid & 15;

  // tanh-gelu constants: e^{2a}, a = 0.7978845608*(x + 0.044715 x^3)
  constexpr float K0 = 2.0f * 1.4426950408889634f * 0.7978845608028654f;
  constexpr float K1 = K0 * 0.044715f;

  float acc = 0.0f;

  for (int kc = 0; kc < 3; ++kc) {
    const int Kb = kc * 512;
    // --- stage R/C chunk: bf16 -> fp32 LDS
#pragma unroll
    for (int x = 0; x < 4; ++x) {
      int s = tid + 256 * x;          // 0..1023
      int row = s >> 6;               // 0..15
      int k8  = (s & 63) * 8;         // 0..504
      uint4v rv = *(const uint4v*)(wsR + (size_t)(bz * 256 + it * 16 + row) * 1536 + Kb + k8);
      uint4v cv = *(const uint4v*)(wsC + (size_t)(bz * 256 + jt * 16 + row) * 1536 + Kb + k8);
      float rf[8], cf[8];
#pragma unroll
      for (int a = 0; a < 4; ++a) {
        union { unsigned int u; float f; } l0, h0, l1, h1;
        l0.u = rv[a] << 16; h0.u = rv[a] & 0xffff0000u;
        l1.u = cv[a] << 16; h1.u = cv[a] & 0xffff0000u;
        rf[2 * a] = l0.f; rf[2 * a + 1] = h0.f;
        cf[2 * a] = l1.f; cf[2 * a + 1] = h1.f;
      }
      float* rd = &Rs[row * 516 + k8];
      float* cd = &Cs[row * 516 + k8];
      *(float4v*)rd       = float4v{rf[0], rf[1], rf[2], rf[3]};
      *(float4v*)(rd + 4) = float4v{rf[4], rf[5], rf[6], rf[7]};
      *(float4v*)cd       = float4v{cf[0], cf[1], cf[2], cf[3]};
      *(float4v*)(cd + 4) = float4v{cf[4], cf[5], cf[6], cf[7]};
    }
    Ws[tid]       = w2[Kb + tid];
    Ws[tid + 256] = w2[Kb + tid + 256];
    __syncthreads();

    const float* rp = &Rs[i * 516];
    const float* cp = &Cs[j * 516];
#pragma unroll 2
    for (int k = 0; k < 512; k += 4) {
      float4v rv = *(const float4v*)(rp + k);
      float4v cv = *(const float4v*)(cp + k);
      float4v wv = *(const float4v*)(&Ws[k]);
#pragma unroll
      for (int d = 0; d < 4; ++d) {
        float x  = rv[d] + cv[d];
        float x2 = x * x;
        float e  = __builtin_amdgcn_exp2f(x * (K0 + K1 * x2));  // e^{2a}
        float rr = __builtin_amdgcn_rcpf(1.0f + e);
        float g  = x - x * rr;  // x*(1 - 1/(1+e^{2a})) = tanh-form gelu
        acc += g * wv[d];
      }
    }
    __syncthreads();
  }

  size_t idx = ((size_t)bz * 256 + it * 16 + i) * 256 + (jt * 16 + j);
  out[idx] = acc + b2[0];
}

// ---------------- launch ----------------
extern "C" void kernel_launch(void* const* d_in, const int* in_sizes, int n_in,
                              void* d_out, int out_size, void* d_ws, size_t ws_size,
                              hipStream_t stream) {
  const float* hidden  = (const float*)d_in[0];
  const float* w_start = (const float*)d_in[1];
  const float* b_start = (const float*)d_in[2];
  const float* w_end   = (const float*)d_in[3];
  const float* b_end   = (const float*)d_in[4];
  const float* w1      = (const float*)d_in[5];
  const float* b1      = (const float*)d_in[6];
  const float* w2      = (const float*)d_in[7];
  const float* b2      = (const float*)d_in[8];

  float* out = (float*)d_out;
  unsigned short* wsR = (unsigned short*)d_ws;        // [512*1536] bf16
  unsigned short* wsC = wsR + (size_t)512 * 1536;     // [512*1536] bf16  (3 MB total)

  logits_kernel<<<dim3(32), dim3(256), 0, stream>>>(hidden, w_start, b_start, w_end, b_end, out);
  proj_kernel<<<dim3(24, 8, 2), dim3(256), 0, stream>>>(hidden, w1, b1, wsR, wsC);
  match_kernel<<<dim3(16, 16, 2), dim3(256), 0, stream>>>(wsR, wsC, w2, b2, out + 1024);
}

// Round 3
// 169.115 us; speedup vs baseline: 1.0129x; 1.0129x over previous
//
#include <hip/hip_runtime.h>
#include <stdint.h>

// ---------- types ----------
typedef __attribute__((ext_vector_type(8))) __bf16 bf16x8;   // MFMA A/B frag (4 VGPRs)
typedef __attribute__((ext_vector_type(4))) float  floatx4;  // MFMA C/D frag
typedef __attribute__((ext_vector_type(4))) unsigned int uint4v;
typedef __attribute__((ext_vector_type(4))) float  float4v;

__device__ __forceinline__ float bf2f(unsigned short h) {
  union { unsigned int u; float f; } x; x.u = ((unsigned int)h) << 16; return x.f;
}
__device__ __forceinline__ unsigned short f2bf(float f) {
  union { float f; unsigned int u; } x; x.f = f;
  unsigned int r = x.u + 0x7fffu + ((x.u >> 16) & 1u);  // RNE
  return (unsigned short)(r >> 16);
}

// async 16B/lane global -> LDS (lane i lands at ldsbase + i*16; ldsbase wave-uniform)
__device__ __forceinline__ void async16(const void* g, void* l) {
  __builtin_amdgcn_global_load_lds(
      (const __attribute__((address_space(1))) unsigned int*)g,
      (__attribute__((address_space(3))) unsigned int*)l, 16, 0, 0);
}

// ---------------- kernel 1: start/end logits (pure fp32) ----------------
__global__ __launch_bounds__(256) void logits_kernel(
    const float* __restrict__ hidden, const float* __restrict__ w_start,
    const float* __restrict__ b_start, const float* __restrict__ w_end,
    const float* __restrict__ b_end, float* __restrict__ out) {
  const int tid  = threadIdx.x;
  const int lane = tid & 63;
  const int wv   = tid >> 6;
  const int wg   = blockIdx.x * 4 + wv;

  float wsv[12], wev[12];
#pragma unroll
  for (int t = 0; t < 12; ++t) {
    wsv[t] = w_start[lane + 64 * t];
    wev[t] = w_end[lane + 64 * t];
  }
  const float bs = b_start[0];
  const float be = b_end[0];

#pragma unroll
  for (int r = 0; r < 4; ++r) {
    int row = wg * 4 + r;
    const float* h = hidden + (size_t)row * 768;
    float ps = 0.f, pe = 0.f;
#pragma unroll
    for (int t = 0; t < 12; ++t) {
      float hv = h[lane + 64 * t];
      ps += hv * wsv[t];
      pe += hv * wev[t];
    }
#pragma unroll
    for (int off = 32; off >= 1; off >>= 1) {
      ps += __shfl_xor(ps, off, 64);
      pe += __shfl_xor(pe, off, 64);
    }
    if (lane == 0) { out[row] = ps + bs; out[512 + row] = pe + be; }
  }
}

// ---------------- cvt_hidden: fp32 [512,768] -> bf16 row-major ----------------
__global__ __launch_bounds__(256) void cvt_hidden_kernel(
    const float* __restrict__ src, unsigned short* __restrict__ dst) {
  int idx = (blockIdx.x * 256 + threadIdx.x) * 8;  // 192 blocks covers 512*768
  float4v a = *(const float4v*)(src + idx);
  float4v b = *(const float4v*)(src + idx + 4);
  uint4v o;
  o[0] = (unsigned int)f2bf(a[0]) | ((unsigned int)f2bf(a[1]) << 16);
  o[1] = (unsigned int)f2bf(a[2]) | ((unsigned int)f2bf(a[3]) << 16);
  o[2] = (unsigned int)f2bf(b[0]) | ((unsigned int)f2bf(b[1]) << 16);
  o[3] = (unsigned int)f2bf(b[2]) | ((unsigned int)f2bf(b[3]) << 16);
  *(uint4v*)(dst + idx) = o;
}

// ---------------- cvt_w1t: w1 fp32 [1536,1536] -> w1T bf16 [3072,768] ----------------
// w1T[n][k] = (n<1536) ? w1[k][n] : w1[768+k][n-1536]. LDS-tiled 64x64 transpose.
// grid (24 n-tiles, 12 k-tiles, 2 halves)
__global__ __launch_bounds__(256) void cvt_w1t_kernel(
    const float* __restrict__ w1, unsigned short* __restrict__ w1T) {
  __shared__ unsigned short Ls[64 * 72];  // [k_local][n_local], stride 72
  const int t  = threadIdx.x;
  const int n0 = blockIdx.x * 64;
  const int k0 = blockIdx.y * 64;
  const int z  = blockIdx.z;

  // read: row kl = t>>2, cols (t&3)*16 .. +15 (coalesced), cvt, LDS store
  {
    const int kl = t >> 2, c = t & 3;
    const float* sp = w1 + (size_t)(z * 768 + k0 + kl) * 1536 + n0 + c * 16;
    unsigned short* lp = &Ls[kl * 72 + c * 16];
#pragma unroll
    for (int q = 0; q < 4; ++q) {
      float4v v = *(const float4v*)(sp + q * 4);
      uint4v o;  // pack into 2 u32 -> use half of uint4... pack 4 floats = 2 u32
      unsigned int u0 = (unsigned int)f2bf(v[0]) | ((unsigned int)f2bf(v[1]) << 16);
      unsigned int u1 = (unsigned int)f2bf(v[2]) | ((unsigned int)f2bf(v[3]) << 16);
      *(unsigned int*)(lp + q * 4)     = u0;
      *(unsigned int*)(lp + q * 4 + 2) = u1;
      (void)o;
    }
  }
  __syncthreads();
  // write: out-row nl = t>>2, k chunk (t&3)*16 .. +15 (coalesced b128 stores)
  {
    const int nl = t >> 2, c = t & 3;
    unsigned short tmp[16];
#pragma unroll
    for (int x = 0; x < 16; ++x) tmp[x] = Ls[(c * 16 + x) * 72 + nl];
    uint4v o;
#pragma unroll
    for (int q = 0; q < 4; ++q)
      o[q] = (unsigned int)tmp[4 * q] | ((unsigned int)tmp[4 * q + 1] << 16) |
             0;  // low pair; high pair below
    // pack properly: each u32 = two bf16
    o[0] = (unsigned int)tmp[0] | ((unsigned int)tmp[1] << 16);
    o[1] = (unsigned int)tmp[2] | ((unsigned int)tmp[3] << 16);
    o[2] = (unsigned int)tmp[4] | ((unsigned int)tmp[5] << 16);
    o[3] = (unsigned int)tmp[6] | ((unsigned int)tmp[7] << 16);
    uint4v o2;
    o2[0] = (unsigned int)tmp[8]  | ((unsigned int)tmp[9]  << 16);
    o2[1] = (unsigned int)tmp[10] | ((unsigned int)tmp[11] << 16);
    o2[2] = (unsigned int)tmp[12] | ((unsigned int)tmp[13] << 16);
    o2[3] = (unsigned int)tmp[14] | ((unsigned int)tmp[15] << 16);
    unsigned short* dp = w1T + (size_t)(z * 1536 + n0 + nl) * 768 + k0 + c * 16;
    *(uint4v*)dp       = o;
    *(uint4v*)(dp + 8) = o2;
  }
}

// ---------------- proj_gemm: C[m][n] = sum_k A[m][k]*Bt[n][k] ----------------
// A = hid_bf16 [512][768], Bt = w1T [3072][768]. Tile 64x64, BK=64, 4 waves,
// wave = 32x32 quadrant. Staging: global_load_lds 16B into fragment-direct LDS
// (index (kq*64+row)*8, kq=k/8). grid (48 n, 8 m).
__global__ __launch_bounds__(256) void proj_gemm_kernel(
    const unsigned short* __restrict__ hidbf,  // [512,768]
    const unsigned short* __restrict__ w1T,    // [3072,768]
    const float* __restrict__ b1,              // [1536] fp32
    unsigned short* __restrict__ wsR,          // [512,1536] bf16
    unsigned short* __restrict__ wsC) {        // [512,1536] bf16
  __shared__ short As[8 * 64 * 8];  // 8KB
  __shared__ short Bs[8 * 64 * 8];  // 8KB

  const int tid  = threadIdx.x;
  const int lane = tid & 63;
  const int wave = tid >> 6;
  const int wr = wave >> 1, wc = wave & 1;
  const int m0 = blockIdx.y * 64;
  const int n0 = blockIdx.x * 64;
  const int q = lane >> 4, l15 = lane & 15;

  floatx4 acc[2][2] = {};

  for (int ko = 0; ko < 768; ko += 64) {
#pragma unroll
    for (int x = 0; x < 2; ++x) {
      int kq = wave * 2 + x;
      async16(hidbf + (size_t)(m0 + lane) * 768 + ko + kq * 8, &As[kq * 64 * 8]);
      async16(w1T   + (size_t)(n0 + lane) * 768 + ko + kq * 8, &Bs[kq * 64 * 8]);
    }
    __syncthreads();

#pragma unroll
    for (int s = 0; s < 2; ++s) {
      bf16x8 a0 = *(const bf16x8*)(&As[((4 * s + q) * 64 + 32 * wr + l15) * 8]);
      bf16x8 a1 = *(const bf16x8*)(&As[((4 * s + q) * 64 + 32 * wr + 16 + l15) * 8]);
      bf16x8 b0 = *(const bf16x8*)(&Bs[((4 * s + q) * 64 + 32 * wc + l15) * 8]);
      bf16x8 b1f = *(const bf16x8*)(&Bs[((4 * s + q) * 64 + 32 * wc + 16 + l15) * 8]);
      acc[0][0] = __builtin_amdgcn_mfma_f32_16x16x32_bf16(a0, b0,  acc[0][0], 0, 0, 0);
      acc[0][1] = __builtin_amdgcn_mfma_f32_16x16x32_bf16(a0, b1f, acc[0][1], 0, 0, 0);
      acc[1][0] = __builtin_amdgcn_mfma_f32_16x16x32_bf16(a1, b0,  acc[1][0], 0, 0, 0);
      acc[1][1] = __builtin_amdgcn_mfma_f32_16x16x32_bf16(a1, b1f, acc[1][1], 0, 0, 0);
    }
    __syncthreads();
  }

  // epilogue: C/D layout col=lane&15, row=(lane>>4)*4+reg [m89]
  const bool isR = (n0 < 1536);
#pragma unroll
  for (int mi = 0; mi < 2; ++mi) {
#pragma unroll
    for (int ni = 0; ni < 2; ++ni) {
      int ng = n0 + 32 * wc + 16 * ni + l15;
      int col = isR ? ng : (ng - 1536);
      float bias = isR ? b1[col] : 0.0f;
      unsigned short* outp = isR ? wsR : wsC;
#pragma unroll
      for (int r = 0; r < 4; ++r) {
        int rowg = m0 + 32 * wr + 16 * mi + q * 4 + r;
        outp[(size_t)rowg * 1536 + col] = f2bf(acc[mi][ni][r] + bias);
      }
    }
  }
}

// ---------------- FALLBACK proj (R2 version, used when ws is small) ----------------
__global__ __launch_bounds__(256, 4) void proj_kernel_slow(
    const float* __restrict__ hidden, const float* __restrict__ w1,
    const float* __restrict__ b1, unsigned short* __restrict__ wsR,
    unsigned short* __restrict__ wsC) {
  __shared__ short As[4 * 64 * 8];
  __shared__ short Bs[4 * 64 * 8];
  const int tid  = threadIdx.x;
  const int lane = tid & 63;
  const int wave = tid >> 6;
  const int wr = wave >> 1, wc = wave & 1;
  const int m0 = blockIdx.y * 64;
  const int n0 = blockIdx.x * 64;
  const int zh = blockIdx.z;
  const int kbase = zh * 768;
  floatx4 acc[2][2] = {};
  const int a_row = tid >> 2, a_q = tid & 3;
  const int b_n = tid & 63, b_kg = tid >> 6;
  const int q = lane >> 4, l15 = lane & 15;
  for (int ko = 0; ko < 768; ko += 32) {
    const float* hp = hidden + (size_t)(m0 + a_row) * 768 + ko + a_q * 8;
    float4v h0 = *(const float4v*)(hp);
    float4v h1 = *(const float4v*)(hp + 4);
    uint4v av;
    av[0] = (unsigned int)f2bf(h0[0]) | ((unsigned int)f2bf(h0[1]) << 16);
    av[1] = (unsigned int)f2bf(h0[2]) | ((unsigned int)f2bf(h0[3]) << 16);
    av[2] = (unsigned int)f2bf(h1[0]) | ((unsigned int)f2bf(h1[1]) << 16);
    av[3] = (unsigned int)f2bf(h1[2]) | ((unsigned int)f2bf(h1[3]) << 16);
    *(uint4v*)(&As[(a_q * 64 + a_row) * 8]) = av;
    const float* bp = w1 + (size_t)(kbase + ko + b_kg * 8) * 1536 + n0 + b_n;
    uint4v pv;
#pragma unroll
    for (int a = 0; a < 4; ++a) {
      unsigned int lo = f2bf(bp[(size_t)(2 * a) * 1536]);
      unsigned int hi = f2bf(bp[(size_t)(2 * a + 1) * 1536]);
      pv[a] = lo | (hi << 16);
    }
    *(uint4v*)(&Bs[(b_kg * 64 + b_n) * 8]) = pv;
    __syncthreads();
    bf16x8 af0 = *(const bf16x8*)(&As[(q * 64 + 32 * wr + l15) * 8]);
    bf16x8 af1 = *(const bf16x8*)(&As[(q * 64 + 32 * wr + 16 + l15) * 8]);
    bf16x8 bg0 = *(const bf16x8*)(&Bs[(q * 64 + 32 * wc + l15) * 8]);
    bf16x8 bg1 = *(const bf16x8*)(&Bs[(q * 64 + 32 * wc + 16 + l15) * 8]);
    acc[0][0] = __builtin_amdgcn_mfma_f32_16x16x32_bf16(af0, bg0, acc[0][0], 0, 0, 0);
    acc[0][1] = __builtin_amdgcn_mfma_f32_16x16x32_bf16(af0, bg1, acc[0][1], 0, 0, 0);
    acc[1][0] = __builtin_amdgcn_mfma_f32_16x16x32_bf16(af1, bg0, acc[1][0], 0, 0, 0);
    acc[1][1] = __builtin_amdgcn_mfma_f32_16x16x32_bf16(af1, bg1, acc[1][1], 0, 0, 0);
    __syncthreads();
  }
  unsigned short* outp = (zh == 0) ? wsR : wsC;
#pragma unroll
  for (int mi = 0; mi < 2; ++mi) {
#pragma unroll
    for (int ni = 0; ni < 2; ++ni) {
      int colg = n0 + 32 * wc + 16 * ni + l15;
      float bias = (zh == 0) ? b1[colg] : 0.0f;
#pragma unroll
      for (int r = 0; r < 4; ++r) {
        int rowg = m0 + 32 * wr + 16 * mi + q * 4 + r;
        outp[(size_t)rowg * 1536 + colg] = f2bf(acc[mi][ni][r] + bias);
      }
    }
  }
}

// ---------------- kernel 3: pairwise gelu-match (v2) ----------------
// K chunked 6x256, fp32 LDS stride 260 (conflict-free inner reads), 34.3KB -> 4 blk/CU.
__global__ __launch_bounds__(256) void match_kernel(
    const unsigned short* __restrict__ wsR,
    const unsigned short* __restrict__ wsC,
    const float* __restrict__ w2, const float* __restrict__ b2,
    float* __restrict__ out) {
  __shared__ float Rs[16 * 260];
  __shared__ float Cs[16 * 260];
  __shared__ float Ws[256];

  const int tid = threadIdx.x;
  const int jt = blockIdx.x, it = blockIdx.y, bz = blockIdx.z;
  const int i = tid >> 4, j = tid & 15;

  constexpr float K0 = 2.0f * 1.4426950408889634f * 0.7978845608028654f;
  constexpr float K1 = K0 * 0.044715f;

  float a0 = 0.f, a1 = 0.f, a2 = 0.f, a3 = 0.f;

  const int srow = tid >> 4;   // 0..15
  const int scc  = tid & 15;   // chunk-of-16 within 256

  for (int kc = 0; kc < 6; ++kc) {
    const int Kb = kc * 256;
    // stage: 16 rows x 256 k, bf16 -> fp32
    {
      const unsigned short* rg = wsR + (size_t)(bz * 256 + it * 16 + srow) * 1536 + Kb + scc * 16;
      const unsigned short* cg = wsC + (size_t)(bz * 256 + jt * 16 + srow) * 1536 + Kb + scc * 16;
      uint4v rv0 = *(const uint4v*)rg;
      uint4v rv1 = *(const uint4v*)(rg + 8);
      uint4v cv0 = *(const uint4v*)cg;
      uint4v cv1 = *(const uint4v*)(cg + 8);
      float* rd = &Rs[srow * 260 + scc * 16];
      float* cd = &Cs[srow * 260 + scc * 16];
#pragma unroll
      for (int a = 0; a < 4; ++a) {
        union { unsigned int u; float f; } lo, hi;
        lo.u = rv0[a] << 16; hi.u = rv0[a] & 0xffff0000u;
        rd[2 * a] = lo.f; rd[2 * a + 1] = hi.f;
        lo.u = rv1[a] << 16; hi.u = rv1[a] & 0xffff0000u;
        rd[8 + 2 * a] = lo.f; rd[8 + 2 * a + 1] = hi.f;
        lo.u = cv0[a] << 16; hi.u = cv0[a] & 0xffff0000u;
        cd[2 * a] = lo.f; cd[2 * a + 1] = hi.f;
        lo.u = cv1[a] << 16; hi.u = cv1[a] & 0xffff0000u;
        cd[8 + 2 * a] = lo.f; cd[8 + 2 * a + 1] = hi.f;
      }
      Ws[tid] = w2[Kb + tid];
    }
    __syncthreads();

    const float* rp = &Rs[i * 260];
    const float* cp = &Cs[j * 260];
#pragma unroll 2
    for (int k = 0; k < 256; k += 8) {
      float4v r0 = *(const float4v*)(rp + k);
      float4v r1 = *(const float4v*)(rp + k + 4);
      float4v c0 = *(const float4v*)(cp + k);
      float4v c1 = *(const float4v*)(cp + k + 4);
      float4v w0 = *(const float4v*)(&Ws[k]);
      float4v w1v = *(const float4v*)(&Ws[k + 4]);
#pragma unroll
      for (int d = 0; d < 4; ++d) {
        {
          float x = r0[d] + c0[d];
          float x2 = x * x;
          float e = __builtin_amdgcn_exp2f(x * (K0 + K1 * x2));
          float rr = __builtin_amdgcn_rcpf(1.0f + e);
          float g = x - x * rr;
          if (d == 0) a0 += g * w0[d];
          else if (d == 1) a1 += g * w0[d];
          else if (d == 2) a2 += g * w0[d];
          else a3 += g * w0[d];
        }
        {
          float x = r1[d] + c1[d];
          float x2 = x * x;
          float e = __builtin_amdgcn_exp2f(x * (K0 + K1 * x2));
          float rr = __builtin_amdgcn_rcpf(1.0f + e);
          float g = x - x * rr;
          if (d == 0) a0 += g * w1v[d];
          else if (d == 1) a1 += g * w1v[d];
          else if (d == 2) a2 += g * w1v[d];
          else a3 += g * w1v[d];
        }
      }
    }
    __syncthreads();
  }

  float acc = (a0 + a1) + (a2 + a3);
  size_t idx = ((size_t)bz * 256 + it * 16 + i) * 256 + (jt * 16 + j);
  out[idx] = acc + b2[0];
}

// ---------------- launch ----------------
extern "C" void kernel_launch(void* const* d_in, const int* in_sizes, int n_in,
                              void* d_out, int out_size, void* d_ws, size_t ws_size,
                              hipStream_t stream) {
  const float* hidden  = (const float*)d_in[0];
  const float* w_start = (const float*)d_in[1];
  const float* b_start = (const float*)d_in[2];
  const float* w_end   = (const float*)d_in[3];
  const float* b_end   = (const float*)d_in[4];
  const float* w1      = (const float*)d_in[5];
  const float* b1      = (const float*)d_in[6];
  const float* w2      = (const float*)d_in[7];
  const float* b2      = (const float*)d_in[8];

  float* out = (float*)d_out;
  char* ws = (char*)d_ws;
  unsigned short* wsR = (unsigned short*)(ws);                 // 1,572,864 B
  unsigned short* wsC = (unsigned short*)(ws + 1572864);       // 1,572,864 B
  const size_t FAST_NEED = 8650752;

  logits_kernel<<<dim3(32), dim3(256), 0, stream>>>(hidden, w_start, b_start, w_end, b_end, out);

  if (ws_size >= FAST_NEED) {
    unsigned short* hidbf = (unsigned short*)(ws + 3145728);   //   786,432 B
    unsigned short* w1T   = (unsigned short*)(ws + 3932160);   // 4,718,592 B
    cvt_hidden_kernel<<<dim3(192), dim3(256), 0, stream>>>(hidden, hidbf);
    cvt_w1t_kernel<<<dim3(24, 12, 2), dim3(256), 0, stream>>>(w1, w1T);
    proj_gemm_kernel<<<dim3(48, 8), dim3(256), 0, stream>>>(hidbf, w1T, b1, wsR, wsC);
  } else {
    proj_kernel_slow<<<dim3(24, 8, 2), dim3(256), 0, stream>>>(hidden, w1, b1, wsR, wsC);
  }

  match_kernel<<<dim3(16, 16, 2), dim3(256), 0, stream>>>(wsR, wsC, w2, b2, out + 1024);
}

// Round 4
// 158.220 us; speedup vs baseline: 1.0826x; 1.0689x over previous
//
#include <hip/hip_runtime.h>
#include <stdint.h>

// ---------- types ----------
typedef __attribute__((ext_vector_type(8))) __bf16 bf16x8;   // MFMA A/B frag (4 VGPRs)
typedef __attribute__((ext_vector_type(4))) float  floatx4;  // MFMA C/D frag
typedef __attribute__((ext_vector_type(4))) unsigned int uint4v;
typedef __attribute__((ext_vector_type(4))) float  float4v;

__device__ __forceinline__ float bf2f(unsigned short h) {
  union { unsigned int u; float f; } x; x.u = ((unsigned int)h) << 16; return x.f;
}
__device__ __forceinline__ unsigned short f2bf(float f) {
  union { float f; unsigned int u; } x; x.f = f;
  unsigned int r = x.u + 0x7fffu + ((x.u >> 16) & 1u);  // RNE
  return (unsigned short)(r >> 16);
}

// ---------------- kernel 1: start/end logits (pure fp32) ----------------
__global__ __launch_bounds__(256) void logits_kernel(
    const float* __restrict__ hidden, const float* __restrict__ w_start,
    const float* __restrict__ b_start, const float* __restrict__ w_end,
    const float* __restrict__ b_end, float* __restrict__ out) {
  const int tid  = threadIdx.x;
  const int lane = tid & 63;
  const int wv   = tid >> 6;
  const int wg   = blockIdx.x * 4 + wv;

  float wsv[12], wev[12];
#pragma unroll
  for (int t = 0; t < 12; ++t) {
    wsv[t] = w_start[lane + 64 * t];
    wev[t] = w_end[lane + 64 * t];
  }
  const float bs = b_start[0];
  const float be = b_end[0];

#pragma unroll
  for (int r = 0; r < 4; ++r) {
    int row = wg * 4 + r;
    const float* h = hidden + (size_t)row * 768;
    float ps = 0.f, pe = 0.f;
#pragma unroll
    for (int t = 0; t < 12; ++t) {
      float hv = h[lane + 64 * t];
      ps += hv * wsv[t];
      pe += hv * wev[t];
    }
#pragma unroll
    for (int off = 32; off >= 1; off >>= 1) {
      ps += __shfl_xor(ps, off, 64);
      pe += __shfl_xor(pe, off, 64);
    }
    if (lane == 0) { out[row] = ps + bs; out[512 + row] = pe + be; }
  }
}

// ---------------- init: fill match region with b2 (atomic accumulate base) ----
__global__ __launch_bounds__(256) void init_match_kernel(
    const float* __restrict__ b2, float* __restrict__ outm) {
  float v = b2[0];
  int idx = (blockIdx.x * 256 + threadIdx.x) * 4;  // grid 128 -> 131072 floats
  *(float4v*)(outm + idx) = float4v{v, v, v, v};
}

// ---------------- cvt_w1t: w1 fp32 [1536,1536] -> w1T bf16 [3072,768] ----------
// w1T[z*1536 + n][k] = bf16(w1[z*768 + k][n]).  LDS-tiled 64x64, stride 74 shorts.
// grid (24 n-tiles, 12 k-tiles, 2 halves)
__global__ __launch_bounds__(256) void cvt_w1t_kernel(
    const float* __restrict__ w1, unsigned short* __restrict__ w1T) {
  __shared__ unsigned short Ls[64 * 74];
  const int t  = threadIdx.x;
  const int n0 = blockIdx.x * 64;
  const int k0 = blockIdx.y * 64;
  const int z  = blockIdx.z;

  {  // load: row kl = t>>2 (64 rows), n-chunk c = t&3 (16 cols), cvt to bf16
    const int kl = t >> 2, c = t & 3;
    const float* sp = w1 + (size_t)(z * 768 + k0 + kl) * 1536 + n0 + c * 16;
    unsigned short* lp = &Ls[kl * 74 + c * 16];
#pragma unroll
    for (int q = 0; q < 4; ++q) {
      float4v v = *(const float4v*)(sp + q * 4);
      *(unsigned int*)(lp + q * 4)     = (unsigned int)f2bf(v[0]) | ((unsigned int)f2bf(v[1]) << 16);
      *(unsigned int*)(lp + q * 4 + 2) = (unsigned int)f2bf(v[2]) | ((unsigned int)f2bf(v[3]) << 16);
    }
  }
  __syncthreads();
  {  // store: out-row nl = t>>2, k-chunk c = t&3 (16 k), b128 coalesced stores
    const int nl = t >> 2, c = t & 3;
    unsigned short tmp[16];
#pragma unroll
    for (int x = 0; x < 16; ++x) tmp[x] = Ls[(c * 16 + x) * 74 + nl];
    uint4v o, o2;
    o[0]  = (unsigned int)tmp[0]  | ((unsigned int)tmp[1]  << 16);
    o[1]  = (unsigned int)tmp[2]  | ((unsigned int)tmp[3]  << 16);
    o[2]  = (unsigned int)tmp[4]  | ((unsigned int)tmp[5]  << 16);
    o[3]  = (unsigned int)tmp[6]  | ((unsigned int)tmp[7]  << 16);
    o2[0] = (unsigned int)tmp[8]  | ((unsigned int)tmp[9]  << 16);
    o2[1] = (unsigned int)tmp[10] | ((unsigned int)tmp[11] << 16);
    o2[2] = (unsigned int)tmp[12] | ((unsigned int)tmp[13] << 16);
    o2[3] = (unsigned int)tmp[14] | ((unsigned int)tmp[15] << 16);
    unsigned short* dp = w1T + (size_t)(z * 1536 + n0 + nl) * 768 + k0 + c * 16;
    *(uint4v*)dp       = o;
    *(uint4v*)(dp + 8) = o2;
  }
}

// ---------------- proj_gemm v2: C[m][n] = sum_k hid[m][k]*w1T[n][k] ------------
// A fp32 hidden (inline cvt), B bf16 w1T. 64x64 tile, BK=64, 4 waves (32x32 quad).
// Coalesced b128 loads + fragment-direct ds_write_b128; no async gather.
// grid (48 n, 8 m).
__global__ __launch_bounds__(256) void proj_gemm_kernel(
    const float* __restrict__ hidden,          // [512,768] fp32
    const unsigned short* __restrict__ w1T,    // [3072,768] bf16
    const float* __restrict__ b1,              // [1536] fp32
    unsigned short* __restrict__ wsR,          // [512,1536] bf16
    unsigned short* __restrict__ wsC) {        // [512,1536] bf16
  __shared__ short As[8 * 64 * 8];  // frag-direct: (kq*64+row)*8, kq=k/8
  __shared__ short Bs[8 * 64 * 8];

  const int tid  = threadIdx.x;
  const int lane = tid & 63;
  const int wave = tid >> 6;
  const int wr = wave >> 1, wc = wave & 1;
  const int m0 = blockIdx.y * 64;
  const int n0 = blockIdx.x * 64;
  const int q = lane >> 4, l15 = lane & 15;

  const int srow = tid >> 2;   // 0..63
  const int sc   = tid & 3;    // 16-elem k-chunk -> kq pair {2c, 2c+1}

  floatx4 acc[2][2] = {};

  for (int ko = 0; ko < 768; ko += 64) {
    // --- stage A: 16 fp32 (coalesced float4) -> bf16 -> 2 frag-direct b128 writes
    {
      const float* hp = hidden + (size_t)(m0 + srow) * 768 + ko + sc * 16;
      float4v v0 = *(const float4v*)(hp);
      float4v v1 = *(const float4v*)(hp + 4);
      float4v v2 = *(const float4v*)(hp + 8);
      float4v v3 = *(const float4v*)(hp + 12);
      uint4v w0, w1v;
      w0[0]  = (unsigned int)f2bf(v0[0]) | ((unsigned int)f2bf(v0[1]) << 16);
      w0[1]  = (unsigned int)f2bf(v0[2]) | ((unsigned int)f2bf(v0[3]) << 16);
      w0[2]  = (unsigned int)f2bf(v1[0]) | ((unsigned int)f2bf(v1[1]) << 16);
      w0[3]  = (unsigned int)f2bf(v1[2]) | ((unsigned int)f2bf(v1[3]) << 16);
      w1v[0] = (unsigned int)f2bf(v2[0]) | ((unsigned int)f2bf(v2[1]) << 16);
      w1v[1] = (unsigned int)f2bf(v2[2]) | ((unsigned int)f2bf(v2[3]) << 16);
      w1v[2] = (unsigned int)f2bf(v3[0]) | ((unsigned int)f2bf(v3[1]) << 16);
      w1v[3] = (unsigned int)f2bf(v3[2]) | ((unsigned int)f2bf(v3[3]) << 16);
      *(uint4v*)(&As[((2 * sc)     * 64 + srow) * 8]) = w0;
      *(uint4v*)(&As[((2 * sc + 1) * 64 + srow) * 8]) = w1v;
    }
    // --- stage B: 16 bf16 x2 (coalesced uint4) -> 2 frag-direct b128 writes
    {
      const unsigned short* bp = w1T + (size_t)(n0 + srow) * 768 + ko + sc * 16;
      uint4v b0 = *(const uint4v*)(bp);
      uint4v b1v = *(const uint4v*)(bp + 8);
      *(uint4v*)(&Bs[((2 * sc)     * 64 + srow) * 8]) = b0;
      *(uint4v*)(&Bs[((2 * sc + 1) * 64 + srow) * 8]) = b1v;
    }
    __syncthreads();

#pragma unroll
    for (int s = 0; s < 2; ++s) {
      bf16x8 a0 = *(const bf16x8*)(&As[((4 * s + q) * 64 + 32 * wr + l15) * 8]);
      bf16x8 a1 = *(const bf16x8*)(&As[((4 * s + q) * 64 + 32 * wr + 16 + l15) * 8]);
      bf16x8 b0 = *(const bf16x8*)(&Bs[((4 * s + q) * 64 + 32 * wc + l15) * 8]);
      bf16x8 b1f = *(const bf16x8*)(&Bs[((4 * s + q) * 64 + 32 * wc + 16 + l15) * 8]);
      acc[0][0] = __builtin_amdgcn_mfma_f32_16x16x32_bf16(a0, b0,  acc[0][0], 0, 0, 0);
      acc[0][1] = __builtin_amdgcn_mfma_f32_16x16x32_bf16(a0, b1f, acc[0][1], 0, 0, 0);
      acc[1][0] = __builtin_amdgcn_mfma_f32_16x16x32_bf16(a1, b0,  acc[1][0], 0, 0, 0);
      acc[1][1] = __builtin_amdgcn_mfma_f32_16x16x32_bf16(a1, b1f, acc[1][1], 0, 0, 0);
    }
    __syncthreads();
  }

  // epilogue: C/D layout col=lane&15, row=(lane>>4)*4+reg [m89]
  const bool isR = (n0 < 1536);
#pragma unroll
  for (int mi = 0; mi < 2; ++mi) {
#pragma unroll
    for (int ni = 0; ni < 2; ++ni) {
      int ng = n0 + 32 * wc + 16 * ni + l15;
      int col = isR ? ng : (ng - 1536);
      float bias = isR ? b1[col] : 0.0f;
      unsigned short* outp = isR ? wsR : wsC;
#pragma unroll
      for (int r = 0; r < 4; ++r) {
        int rowg = m0 + 32 * wr + 16 * mi + q * 4 + r;
        outp[(size_t)rowg * 1536 + col] = f2bf(acc[mi][ni][r] + bias);
      }
    }
  }
}

// ---------------- FALLBACK proj (proven R2 version, small-ws path) ----------------
__global__ __launch_bounds__(256, 4) void proj_kernel_slow(
    const float* __restrict__ hidden, const float* __restrict__ w1,
    const float* __restrict__ b1, unsigned short* __restrict__ wsR,
    unsigned short* __restrict__ wsC) {
  __shared__ short As[4 * 64 * 8];
  __shared__ short Bs[4 * 64 * 8];
  const int tid  = threadIdx.x;
  const int lane = tid & 63;
  const int wave = tid >> 6;
  const int wr = wave >> 1, wc = wave & 1;
  const int m0 = blockIdx.y * 64;
  const int n0 = blockIdx.x * 64;
  const int zh = blockIdx.z;
  const int kbase = zh * 768;
  floatx4 acc[2][2] = {};
  const int a_row = tid >> 2, a_q = tid & 3;
  const int b_n = tid & 63, b_kg = tid >> 6;
  const int q = lane >> 4, l15 = lane & 15;
  for (int ko = 0; ko < 768; ko += 32) {
    const float* hp = hidden + (size_t)(m0 + a_row) * 768 + ko + a_q * 8;
    float4v h0 = *(const float4v*)(hp);
    float4v h1 = *(const float4v*)(hp + 4);
    uint4v av;
    av[0] = (unsigned int)f2bf(h0[0]) | ((unsigned int)f2bf(h0[1]) << 16);
    av[1] = (unsigned int)f2bf(h0[2]) | ((unsigned int)f2bf(h0[3]) << 16);
    av[2] = (unsigned int)f2bf(h1[0]) | ((unsigned int)f2bf(h1[1]) << 16);
    av[3] = (unsigned int)f2bf(h1[2]) | ((unsigned int)f2bf(h1[3]) << 16);
    *(uint4v*)(&As[(a_q * 64 + a_row) * 8]) = av;
    const float* bp = w1 + (size_t)(kbase + ko + b_kg * 8) * 1536 + n0 + b_n;
    uint4v pv;
#pragma unroll
    for (int a = 0; a < 4; ++a) {
      unsigned int lo = f2bf(bp[(size_t)(2 * a) * 1536]);
      unsigned int hi = f2bf(bp[(size_t)(2 * a + 1) * 1536]);
      pv[a] = lo | (hi << 16);
    }
    *(uint4v*)(&Bs[(b_kg * 64 + b_n) * 8]) = pv;
    __syncthreads();
    bf16x8 af0 = *(const bf16x8*)(&As[(q * 64 + 32 * wr + l15) * 8]);
    bf16x8 af1 = *(const bf16x8*)(&As[(q * 64 + 32 * wr + 16 + l15) * 8]);
    bf16x8 bg0 = *(const bf16x8*)(&Bs[(q * 64 + 32 * wc + l15) * 8]);
    bf16x8 bg1 = *(const bf16x8*)(&Bs[(q * 64 + 32 * wc + 16 + l15) * 8]);
    acc[0][0] = __builtin_amdgcn_mfma_f32_16x16x32_bf16(af0, bg0, acc[0][0], 0, 0, 0);
    acc[0][1] = __builtin_amdgcn_mfma_f32_16x16x32_bf16(af0, bg1, acc[0][1], 0, 0, 0);
    acc[1][0] = __builtin_amdgcn_mfma_f32_16x16x32_bf16(af1, bg0, acc[1][0], 0, 0, 0);
    acc[1][1] = __builtin_amdgcn_mfma_f32_16x16x32_bf16(af1, bg1, acc[1][1], 0, 0, 0);
    __syncthreads();
  }
  unsigned short* outp = (zh == 0) ? wsR : wsC;
#pragma unroll
  for (int mi = 0; mi < 2; ++mi) {
#pragma unroll
    for (int ni = 0; ni < 2; ++ni) {
      int colg = n0 + 32 * wc + 16 * ni + l15;
      float bias = (zh == 0) ? b1[colg] : 0.0f;
#pragma unroll
      for (int r = 0; r < 4; ++r) {
        int rowg = m0 + 32 * wr + 16 * mi + q * 4 + r;
        outp[(size_t)rowg * 1536 + colg] = f2bf(acc[mi][ni][r] + bias);
      }
    }
  }
}

// ---------------- kernel 3: pairwise gelu-match (K-split x2, atomic) ----------
// grid (16 jt, 16 it, 4): z = bz*2 + kh. Each block: 16x16 outputs, K-half 768
// (3 chunks of 256). Partials accumulated via unsafeAtomicAdd into out (init=b2).
__global__ __launch_bounds__(256) void match_kernel(
    const unsigned short* __restrict__ wsR,
    const unsigned short* __restrict__ wsC,
    const float* __restrict__ w2,
    float* __restrict__ outm) {
  __shared__ float Rs[16 * 260];
  __shared__ float Cs[16 * 260];
  __shared__ float Ws[256];

  const int tid = threadIdx.x;
  const int jt = blockIdx.x, it = blockIdx.y;
  const int bz = blockIdx.z >> 1, kh = blockIdx.z & 1;
  const int i = tid >> 4, j = tid & 15;

  constexpr float K0 = 2.0f * 1.4426950408889634f * 0.7978845608028654f;
  constexpr float K1 = K0 * 0.044715f;

  float a0 = 0.f, a1 = 0.f, a2 = 0.f, a3 = 0.f;

  const int srow = tid >> 4;   // 0..15
  const int scc  = tid & 15;   // 16-elem chunk within 256

  for (int kc = 0; kc < 3; ++kc) {
    const int Kb = kh * 768 + kc * 256;
    {  // stage 16 rows x 256 k: bf16 -> fp32, float4 LDS stores
      const unsigned short* rg = wsR + (size_t)(bz * 256 + it * 16 + srow) * 1536 + Kb + scc * 16;
      const unsigned short* cg = wsC + (size_t)(bz * 256 + jt * 16 + srow) * 1536 + Kb + scc * 16;
      uint4v rv0 = *(const uint4v*)rg;
      uint4v rv1 = *(const uint4v*)(rg + 8);
      uint4v cv0 = *(const uint4v*)cg;
      uint4v cv1 = *(const uint4v*)(cg + 8);
      float* rd = &Rs[srow * 260 + scc * 16];
      float* cd = &Cs[srow * 260 + scc * 16];
      float4v t0, t1, t2, t3;
#pragma unroll
      for (int a = 0; a < 2; ++a) {
        union { unsigned int u; float f; } lo, hi;
        lo.u = rv0[2*a] << 16;   hi.u = rv0[2*a] & 0xffff0000u;
        t0[2*a] = lo.f; t0[2*a+1] = hi.f;
        lo.u = rv0[2*a+1] << 16; hi.u = rv0[2*a+1] & 0xffff0000u;
        t1[2*a] = lo.f; t1[2*a+1] = hi.f;
        lo.u = rv1[2*a] << 16;   hi.u = rv1[2*a] & 0xffff0000u;
        t2[2*a] = lo.f; t2[2*a+1] = hi.f;
        lo.u = rv1[2*a+1] << 16; hi.u = rv1[2*a+1] & 0xffff0000u;
        t3[2*a] = lo.f; t3[2*a+1] = hi.f;
      }
      // fix interleave: rebuild in order (u32 a holds elems 2a,2a+1)
      float4v r0 = float4v{t0[0], t0[1], t1[0], t1[1]};
      float4v r1 = float4v{t0[2], t0[3], t1[2], t1[3]};
      float4v r2 = float4v{t2[0], t2[1], t3[0], t3[1]};
      float4v r3 = float4v{t2[2], t2[3], t3[2], t3[3]};
      *(float4v*)rd        = r0;
      *(float4v*)(rd + 4)  = r1;
      *(float4v*)(rd + 8)  = r2;
      *(float4v*)(rd + 12) = r3;
#pragma unroll
      for (int a = 0; a < 2; ++a) {
        union { unsigned int u; float f; } lo, hi;
        lo.u = cv0[2*a] << 16;   hi.u = cv0[2*a] & 0xffff0000u;
        t0[2*a] = lo.f; t0[2*a+1] = hi.f;
        lo.u = cv0[2*a+1] << 16; hi.u = cv0[2*a+1] & 0xffff0000u;
        t1[2*a] = lo.f; t1[2*a+1] = hi.f;
        lo.u = cv1[2*a] << 16;   hi.u = cv1[2*a] & 0xffff0000u;
        t2[2*a] = lo.f; t2[2*a+1] = hi.f;
        lo.u = cv1[2*a+1] << 16; hi.u = cv1[2*a+1] & 0xffff0000u;
        t3[2*a] = lo.f; t3[2*a+1] = hi.f;
      }
      float4v c0 = float4v{t0[0], t0[1], t1[0], t1[1]};
      float4v c1 = float4v{t0[2], t0[3], t1[2], t1[3]};
      float4v c2 = float4v{t2[0], t2[1], t3[0], t3[1]};
      float4v c3 = float4v{t2[2], t2[3], t3[2], t3[3]};
      *(float4v*)cd        = c0;
      *(float4v*)(cd + 4)  = c1;
      *(float4v*)(cd + 8)  = c2;
      *(float4v*)(cd + 12) = c3;
      Ws[tid] = w2[Kb + tid];
    }
    __syncthreads();

    const float* rp = &Rs[i * 260];
    const float* cp = &Cs[j * 260];
#pragma unroll 2
    for (int k = 0; k < 256; k += 8) {
      float4v r0 = *(const float4v*)(rp + k);
      float4v r1 = *(const float4v*)(rp + k + 4);
      float4v c0 = *(const float4v*)(cp + k);
      float4v c1 = *(const float4v*)(cp + k + 4);
      float4v w0 = *(const float4v*)(&Ws[k]);
      float4v w1v = *(const float4v*)(&Ws[k + 4]);
#pragma unroll
      for (int d = 0; d < 4; ++d) {
        {
          float x = r0[d] + c0[d];
          float x2 = x * x;
          float e = __builtin_amdgcn_exp2f(x * (K0 + K1 * x2));
          float rr = __builtin_amdgcn_rcpf(1.0f + e);
          float g = x - x * rr;
          if (d == 0) a0 += g * w0[d];
          else if (d == 1) a1 += g * w0[d];
          else if (d == 2) a2 += g * w0[d];
          else a3 += g * w0[d];
        }
        {
          float x = r1[d] + c1[d];
          float x2 = x * x;
          float e = __builtin_amdgcn_exp2f(x * (K0 + K1 * x2));
          float rr = __builtin_amdgcn_rcpf(1.0f + e);
          float g = x - x * rr;
          if (d == 0) a0 += g * w1v[d];
          else if (d == 1) a1 += g * w1v[d];
          else if (d == 2) a2 += g * w1v[d];
          else a3 += g * w1v[d];
        }
      }
    }
    __syncthreads();
  }

  float acc = (a0 + a1) + (a2 + a3);
  size_t idx = ((size_t)bz * 256 + it * 16 + i) * 256 + (jt * 16 + j);
  unsafeAtomicAdd(&outm[idx], acc);
}

// ---------------- launch ----------------
extern "C" void kernel_launch(void* const* d_in, const int* in_sizes, int n_in,
                              void* d_out, int out_size, void* d_ws, size_t ws_size,
                              hipStream_t stream) {
  const float* hidden  = (const float*)d_in[0];
  const float* w_start = (const float*)d_in[1];
  const float* b_start = (const float*)d_in[2];
  const float* w_end   = (const float*)d_in[3];
  const float* b_end   = (const float*)d_in[4];
  const float* w1      = (const float*)d_in[5];
  const float* b1      = (const float*)d_in[6];
  const float* w2      = (const float*)d_in[7];
  const float* b2      = (const float*)d_in[8];

  float* out = (float*)d_out;
  char* ws = (char*)d_ws;
  unsigned short* wsR = (unsigned short*)(ws);                 // 1,572,864 B
  unsigned short* wsC = (unsigned short*)(ws + 1572864);       // 1,572,864 B
  const size_t FAST_NEED = 7864320;                            // + w1T 4,718,592 B

  logits_kernel<<<dim3(32), dim3(256), 0, stream>>>(hidden, w_start, b_start, w_end, b_end, out);
  init_match_kernel<<<dim3(128), dim3(256), 0, stream>>>(b2, out + 1024);

  if (ws_size >= FAST_NEED) {
    unsigned short* w1T = (unsigned short*)(ws + 3145728);     // 4,718,592 B
    cvt_w1t_kernel<<<dim3(24, 12, 2), dim3(256), 0, stream>>>(w1, w1T);
    proj_gemm_kernel<<<dim3(48, 8), dim3(256), 0, stream>>>(hidden, w1T, b1, wsR, wsC);
  } else {
    proj_kernel_slow<<<dim3(24, 8, 2), dim3(256), 0, stream>>>(hidden, w1, b1, wsR, wsC);
  }

  match_kernel<<<dim3(16, 16, 4), dim3(256), 0, stream>>>(wsR, wsC, w2, out + 1024);
}